// Round 1
// 100.975 us; speedup vs baseline: 1.0056x; 1.0056x over previous
//
#include <hip/hip_runtime.h>
#include <math.h>

#define GH 224
#define GW 224
#define GN (GH*GW)          // 50176
#define NT 25
#define NG 20               // distinct d2 values in 11x11 window
#define CAP 24576           // per-image (birth,death) list capacity (16 segs x 1536)
#define SEGN 16
#define SEGCAP 1536
#define TILES_X 8           // 28 px wide  (8*28 = 224 exact)
#define TILES_Y 16          // 14 px tall  (16*14 = 224 exact)
#define TPI (TILES_X*TILES_Y)   // 128 tiles per image
#define NTILES (12*TPI)         // 1536
#define NSUMJ 588               // 12 images * 49 chunks of 1024 px
#define WTW 40              // w-tile stride (row-major stride-1 access -> conflict-free)
#define WTH 26              // (14+2)+10 tall
#define WTN (WTW*WTH)       // 1040
#define SW 30               // S1/S2 cols (F cols -1..28)
#define SH 26               // S1/S2 rows (w rows of tile)

// ws float offsets:
// [16..784)    minmax replicas: per image 32 x (mn_invbits, mx_bits), uint atomicMax
// [784..976)   per-(image,segment) minima counters (12*16 ints)
// [1024..1624) lam[12][50]
// [1664..2252) 588 per-chunk sum partials
// [4096..)     per-image lists: float2[CAP], segmented 16 x 1536
#define WS_MM   16
#define WS_CTR  784
#define WS_LAM  1024
#define WS_SUMP 1664
#define WS_LIST 4096

// Group table (exact fallback path only): group id per (dy,dx) = rank of its d2
// among the 20 distinct values ascending == stable-argsort run partition
// (HW-verified R4..R12: clip-fill over an equal-d2 run == one clip of run sum).
struct GrpTbl { int g[11][11]; float gd2[NG]; };
constexpr GrpTbl make_g() {
    GrpTbl t{};
    int n = 0;
    for (int v = 0; v <= 50; v++) {
        bool found = false;
        for (int dy = -5; dy <= 5 && !found; dy++)
            for (int dx = -5; dx <= 5 && !found; dx++)
                if (dy*dy + dx*dx == v) found = true;
        if (found) { t.gd2[n] = (float)v; n++; }
    }
    for (int dy = 0; dy < 11; dy++)
        for (int dx = 0; dx < 11; dx++) {
            int d2 = (dy-5)*(dy-5) + (dx-5)*(dx-5);
            for (int k = 0; k < NG; k++)
                if ((float)d2 == t.gd2[k]) t.g[dy][dx] = k;
        }
    return t;
}
constexpr GrpTbl TG = make_g();
__device__ __constant__ float KD2[11] = {25.f,16.f,9.f,4.f,1.f,0.f,1.f,4.f,9.f,16.f,25.f};

// Node 1: zero ctl region [0..1024) (disjoint float4 per block) + sum partials.
__global__ __launch_bounds__(256) void k_sums(const float* __restrict__ in, float* __restrict__ ws) {
    __shared__ float sh4[4];
    int j = blockIdx.x;
    if (j < 256 && threadIdx.x == 0)
        ((float4*)ws)[j] = make_float4(0.f, 0.f, 0.f, 0.f);
    int idx = j / 49, chunk = j % 49;
    int cc = idx >> 2, bb = idx & 3;
    const float4* w4 = (const float4*)(in + (size_t)(bb*3 + cc) * GN);
    float4 v = w4[chunk*256 + threadIdx.x];
    float s = v.x + v.y + v.z + v.w;
    #pragma unroll
    for (int off = 32; off; off >>= 1) s += __shfl_down(s, off);
    if ((threadIdx.x & 63) == 0) sh4[threadIdx.x >> 6] = s;
    __syncthreads();
    if (threadIdx.x == 0) ws[WS_SUMP + j] = sh4[0] + sh4[1] + sh4[2] + sh4[3];
}

// Node 2: DTM via separable convolution (clip never binds; per-point check with
// exact grouped fallback) + 3x3 min/max + minima compaction per 28x14 tile.
__global__ __launch_bounds__(256) void k_dtm(const float* __restrict__ in, float* __restrict__ ws) {
    __shared__ float wt[WTN];
    __shared__ float S1[SH*SW], S2[SH*SW];
    __shared__ float Ft[16*32];        // 16 rows x stride 32 (cols 0..29 valid)
    __shared__ float sb[416], sd[416];
    __shared__ float smn[4], smx[4];
    __shared__ float sbound;
    __shared__ int lcnt, gbase;
    const int tid = threadIdx.x;

    int tile_id = blockIdx.x;
    int idx  = tile_id / TPI;
    int trem = tile_id % TPI;
    int tyi = trem / TILES_X, txi = trem % TILES_X;
    int gy = tyi*14, gx = txi*28;      // interior origin
    int cc = idx >> 2, bb = idx & 3;
    const float* w = in + (size_t)(bb*3 + cc) * GN;
    int rep = trem & 31;               // minmax replica
    int seg = trem & 15;               // list segment

    // bound = 0.05 * sum(image) from 49 partials (fixed-order -> identical per image)
    if (tid < 64) {
        float p = (tid < 49) ? ws[WS_SUMP + idx*49 + tid] : 0.f;
        #pragma unroll
        for (int off = 32; off; off >>= 1) p += __shfl_down(p, off);
        if (tid == 0) { sbound = 0.05f * p; lcnt = 0; }
    }

    // stage border-clamped w halo tile 26 x 40
    int wy0 = gy - 6, wx0 = gx - 6;
    if (txi != 0 && txi != TILES_X-1) {
        // x-interior: rows contiguous in global (only y clamps); float2, aligned
        for (int i = tid; i < SH*20; i += 256) {
            int r = i / 20, q = i % 20;
            int yy = wy0 + r; yy = yy < 0 ? 0 : (yy > GH-1 ? GH-1 : yy);
            ((float2*)wt)[r*20 + q] = ((const float2*)(w + yy*GW + wx0))[q];
        }
    } else {
        for (int i = tid; i < WTN; i += 256) {
            int r = i / WTW, q = i % WTW;
            int yy = wy0 + r; yy = yy < 0 ? 0 : (yy > GH-1 ? GH-1 : yy);
            int xx = wx0 + q; xx = xx < 0 ? 0 : (xx > GW-1 ? GW-1 : xx);
            wt[i] = w[yy*GW + xx];
        }
    }
    __syncthreads();

    // horizontal pass: S1 = box sum, S2 = dx^2-weighted sum, per (w-row, F-col)
    for (int e = tid; e < SH*SW; e += 256) {
        int r = e / SW, fc = e % SW;
        int pxc = gx - 1 + fc; pxc = pxc < 0 ? 0 : (pxc > GW-1 ? GW-1 : pxc);
        const float* bp = wt + r*WTW + (pxc - wx0 - 5);
        float s1 = 0.f, s2 = 0.f;
        #pragma unroll
        for (int k = 0; k < 11; k++) {
            float v = bp[k];
            s1 += v;
            s2 = fmaf(KD2[k], v, s2);
        }
        S1[e] = s1; S2[e] = s2;
    }
    __syncthreads();

    // vertical pass: two F-points per thread (rows fy0, fy0+8), col fc
    const bool act = tid < 240;        // 8 row-starts x 30 cols
    int fy0 = act ? tid / 30 : 0;
    int fc  = act ? tid % 30 : 0;
    float bound = sbound;
    float fv[2] = {0.f, 0.f};
    if (act) {
        int pxc = gx - 1 + fc; pxc = pxc < 0 ? 0 : (pxc > GW-1 ? GW-1 : pxc);
        int cb = pxc - wx0 - 5;
        #pragma unroll
        for (int h = 0; h < 2; h++) {
            int fy = fy0 + h*8;
            int py = gy - 1 + fy; int pyc = py < 0 ? 0 : (py > GH-1 ? GH-1 : py);
            int vb = pyc - wy0 - 5;
            float a = 0.f, b2 = 0.f, cumT = 0.f;
            #pragma unroll
            for (int k = 0; k < 11; k++) {
                float s1 = S1[(vb+k)*SW + fc];
                float s2 = S2[(vb+k)*SW + fc];
                a = fmaf(KD2[k], s1, a);
                b2 += s2;
                cumT += s1;
            }
            float acc = a + b2;
            if (bound < cumT) {        // exact grouped path (never for bench input)
                const float* basep = wt + vb*WTW + cb;
                float cum = 0.f; acc = 0.f;
                for (int g = 0; g < NG; g++) {
                    float gs = 0.f;
                    for (int r = 0; r < 11; r++)
                        for (int c = 0; c < 11; c++)
                            if (TG.g[r][c] == g) gs += basep[r*WTW + c];
                    float v = bound - cum;
                    v = v < 0.f ? 0.f : v;
                    v = v > gs ? gs : v;
                    acc = fmaf(v, TG.gd2[g], acc);
                    cum += gs;
                }
            }
            fv[h] = sqrtf(acc / bound + 1e-12f);
            Ft[fy*32 + fc] = fv[h];
        }
    }
    float mnv = INFINITY, mxv = -INFINITY;
    if (act) { mnv = fminf(fv[0], fv[1]); mxv = fmaxf(fv[0], fv[1]); }  // halo = clamped dups, safe
    #pragma unroll
    for (int off = 32; off; off >>= 1) {
        mnv = fminf(mnv, __shfl_down(mnv, off));
        mxv = fmaxf(mxv, __shfl_down(mxv, off));
    }
    if ((tid & 63) == 0) { smn[tid>>6] = mnv; smx[tid>>6] = mxv; }
    __syncthreads();                   // Ft complete + smn/smx ready
    if (tid == 0) {
        float bm = fminf(fminf(smn[0], smn[1]), fminf(smn[2], smn[3]));
        float bX = fmaxf(fmaxf(smx[0], smx[1]), fmaxf(smx[2], smx[3]));
        atomicMax((unsigned int*)&ws[WS_MM + (idx*32 + rep)*2],     ~__float_as_uint(bm));
        atomicMax((unsigned int*)&ws[WS_MM + (idx*32 + rep)*2 + 1],  __float_as_uint(bX));
    }

    // 3x3 is_min / death on 28x14 interior (F rows 1..14, cols 1..28)
    if (act && fc >= 1 && fc <= 28) {
        #pragma unroll
        for (int h = 0; h < 2; h++) {
            int fy = fy0 + h*8;
            if (fy >= 1 && fy <= 14) {
                const float* Fc = Ft + (fy-1)*32 + (fc-1);
                float f = fv[h];
                float mn = f, mx = f;
                #pragma unroll
                for (int dy = 0; dy < 3; dy++)
                    #pragma unroll
                    for (int dx = 0; dx < 3; dx++) {
                        float v = Fc[dy*32 + dx];
                        mn = fminf(mn, v); mx = fmaxf(mx, v);
                    }
                if (f <= mn) {
                    int s = atomicAdd(&lcnt, 1);
                    sb[s] = f; sd[s] = mx;
                }
            }
        }
    }
    __syncthreads();
    if (tid == 0)                      // 8 blocks per (image,segment) counter
        gbase = atomicAdd((int*)ws + WS_CTR + idx*SEGN + seg, lcnt);
    __syncthreads();
    int n = lcnt, gb = gbase;
    float2* list = (float2*)(ws + WS_LIST) + (size_t)idx * CAP + seg * SEGCAP;
    for (int i = tid; i < n; i += 256)
        if (gb + i < SEGCAP) list[gb + i] = make_float2(sb[i], sd[i]);
}

// Node 3: top-2 landscape per (image,t). NO fences/ticket (R12's 40us lesson).
// NEW: prefetch all 16 segment counters (independent loads — the old in-loop
// counter load could not be hoisted past the previous segment's list reads,
// serializing 16 miss+scan rounds), then FLATTEN the 16 segments into one
// grid-stride loop with select-chain addressing so every list load is
// independent and pipelines. Top-2 via exact fmax/fmin is order-invariant,
// so the result is bit-identical to the segment-major order.
__global__ __launch_bounds__(256) void k_top2(float* __restrict__ ws) {
    __shared__ float r0s[4], r1s[4];
    __shared__ float s_tm[2];
    const int tid = threadIdx.x;
    int jb = blockIdx.x;
    int idx = jb / NT, t = jb % NT;

    // prefetch all 16 counters upfront (no prior stores in-kernel -> all issue early)
    int nmv[SEGN];
    #pragma unroll
    for (int s = 0; s < SEGN; s++) {
        int nm = ((const int*)ws)[WS_CTR + idx*SEGN + s];
        nmv[s] = nm < SEGCAP ? nm : SEGCAP;
    }

    // reduce the 32 minmax replicas (one 32-lane shuffle tree)
    if (tid < 32) {
        unsigned mn = ((const unsigned*)ws)[WS_MM + (idx*32 + tid)*2];
        unsigned mx = ((const unsigned*)ws)[WS_MM + (idx*32 + tid)*2 + 1];
        #pragma unroll
        for (int off = 16; off; off >>= 1) {
            unsigned m2 = __shfl_down(mn, off);
            unsigned x2 = __shfl_down(mx, off);
            mn = mn > m2 ? mn : m2;
            mx = mx > x2 ? mx : x2;
        }
        if (tid == 0) { s_tm[0] = __uint_as_float(~mn); s_tm[1] = __uint_as_float(mx); }
    }
    __syncthreads();
    float tmin = s_tm[0], tmax = s_tm[1];
    float tss = tmin + (tmax - tmin) * ((float)t / 24.0f);

    // uniform prefix offsets, constant-indexed (registers, no scratch)
    int off[SEGN+1];
    off[0] = 0;
    #pragma unroll
    for (int s = 0; s < SEGN; s++) off[s+1] = off[s] + nmv[s];
    int total = off[SEGN];
    const float2* base = (const float2*)(ws + WS_LIST) + (size_t)idx * CAP;

    float a0 = 0.f, a1 = 0.f;
    for (int g = tid; g < total; g += 256) {
        // address of flat element g: seg = max{s : off[s] <= g},
        // a = g - off[seg] + seg*SEGCAP. Unrolled select chain, all
        // compile-time indices -> pure VALU, no memory dependence.
        int a = g;
        #pragma unroll
        for (int s = 1; s < SEGN; s++)
            a = (g >= off[s]) ? (g - off[s] + s*SEGCAP) : a;
        float2 p = base[a];
        float v = fmaxf(fminf(tss - p.x, p.y - tss), 0.f);
        float n0 = fmaxf(a0, v);
        a1 = fmaxf(a1, fminf(a0, v));
        a0 = n0;
    }
    #pragma unroll
    for (int off2 = 32; off2; off2 >>= 1) {
        float b0 = __shfl_down(a0, off2);
        float b1 = __shfl_down(a1, off2);
        float n0 = fmaxf(a0, b0);
        a1 = fmaxf(fminf(a0, b0), fmaxf(a1, b1));
        a0 = n0;
    }
    if ((tid & 63) == 0) { r0s[tid>>6] = a0; r1s[tid>>6] = a1; }
    __syncthreads();
    if (tid == 0) {
        float c0 = r0s[0], c1 = r1s[0];
        #pragma unroll
        for (int wv = 1; wv < 4; wv++) {
            float b0 = r0s[wv], b1 = r1s[wv];
            float n0 = fmaxf(c0, b0);
            c1 = fmaxf(fminf(c0, b0), fmaxf(c1, b1));
            c0 = n0;
        }
        ws[WS_LAM + (size_t)idx*50 + t*2    ] = c0;
        ws[WS_LAM + (size_t)idx*50 + t*2 + 1] = c1;
    }
}

// Node 4: linear heads + signal (single block). NEW: stage all weights/biases
// into LDS with one cooperative pass of independent loads (post-poison caches
// are cold; a 4-wave block can't hide scattered in-loop misses), compute from LDS.
__global__ __launch_bounds__(256) void k_head(
        const float* __restrict__ W1, const float* __restrict__ b1,
        const float* __restrict__ W2, const float* __restrict__ b2,
        const float* __restrict__ W3, const float* __restrict__ b3,
        const float* __restrict__ fcw, const float* __restrict__ fcb,
        const float* __restrict__ ws, float* __restrict__ out)
{
    __shared__ float lamS[600];
    __shared__ float xsh[600];
    __shared__ float Wsh[7500];        // W1|W2|W3, 2500 each
    __shared__ float fcwS[1050];
    __shared__ float bS[150];          // b1|b2|b3
    __shared__ float fcbS[7];
    const int tid = threadIdx.x;
    for (int i = tid; i < 600; i += 256) lamS[i] = ws[WS_LAM + i];
    for (int i = tid; i < 2500; i += 256) {
        Wsh[i]        = W1[i];
        Wsh[2500 + i] = W2[i];
        Wsh[5000 + i] = W3[i];
    }
    for (int i = tid; i < 1050; i += 256) fcwS[i] = fcw[i];
    if (tid < 50) { bS[tid] = b1[tid]; bS[50+tid] = b2[tid]; bS[100+tid] = b3[tid]; }
    if (tid < 7) fcbS[tid] = fcb[tid];
    __syncthreads();
    for (int j = tid; j < 600; j += 256) {
        int b = j / 150, r = j % 150, c = r / 50, o = r % 50;
        const float* Wc = Wsh + c*2500;
        const float* lam = lamS + (c*4 + b) * 50;
        float acc = bS[c*50 + o];
        for (int f2 = 0; f2 < 50; f2++) acc += lam[f2] * Wc[o*50 + f2];
        xsh[j] = acc;
    }
    __syncthreads();
    if (tid < 150) {                     // signal = sum_b |x|
        float s = 0.f;
        for (int b = 0; b < 4; b++) s += fabsf(xsh[b*150 + tid]);
        out[28 + tid] = s;
    }
    if (tid < 28) {                      // output = relu(x) @ fc_w.T + fc_b
        int b = tid / 7, o = tid % 7;
        float acc = fcbS[o];
        for (int j = 0; j < 150; j++) acc += fmaxf(xsh[b*150 + j], 0.f) * fcwS[o*150 + j];
        out[b*7 + o] = acc;
    }
}

extern "C" void kernel_launch(void* const* d_in, const int* in_sizes, int n_in,
                              void* d_out, int out_size, void* d_ws, size_t ws_size,
                              hipStream_t stream) {
    const float* in  = (const float*)d_in[0];
    const float* W1  = (const float*)d_in[1];
    const float* b1  = (const float*)d_in[2];
    const float* W2  = (const float*)d_in[3];
    const float* b2  = (const float*)d_in[4];
    const float* W3  = (const float*)d_in[5];
    const float* b3  = (const float*)d_in[6];
    const float* fcw = (const float*)d_in[7];
    const float* fcb = (const float*)d_in[8];
    float* ws  = (float*)d_ws;
    float* out = (float*)d_out;

    k_sums<<<NSUMJ,  256, 0, stream>>>(in, ws);
    k_dtm <<<NTILES, 256, 0, stream>>>(in, ws);
    k_top2<<<300,    256, 0, stream>>>(ws);
    k_head<<<1,      256, 0, stream>>>(W1, b1, W2, b2, W3, b3, fcw, fcb, ws, out);
}